// Round 11
// baseline (32.745 us; speedup 1.0000x reference)
//
#include <hip/hip_runtime.h>
#include <math.h>

// CapLayer fused, R11: factorized routing (no pred), 4 batches per block.
// Hypothesis test: R9/R10 identical at 26.6us despite 3x VMEM cut -> suspect
// ~10ns/WG dispatch floor (2560 WGs ~= 26us). Grid 640 (NT=512): four
// 128-thread units per block, unit u handles b = bq*4+u with the exact R10
// per-unit algorithm; Wk staged once (512 threads = 512 (g,d) items) and
// shared by all 4 units. Units are wave-aligned -> shuffles unchanged.
//   y[g,k] = sum_{i in g} e_i x[k,i]; s[d] = sum Wk[g,k,d] y[g,k] (+bias k=8)
//   u[g,k] = beta sum_d s[d] Wk[g,k,d]; b_i += sum_k u[g,k] x[k,i]
// NO launch_bounds min-waves (R2/R3/R7: every VGPR cap below the working set
// spilled 60-350 MB scratch).

#define G_    32
#define J_    10
#define D_    16
#define NT_   512
#define UN_   4              // batches per block
#define GSW_  148
#define YS_   12

__global__ __launch_bounds__(NT_) void caps_route_kernel(
    const float* __restrict__ x,     // (b, g*8+k, s) flat b*9216 + g*288 + k*36 + s
    const float* __restrict__ Wt,    // (g, j*16+d, k) flat g*1280 + (j*16+d)*8 + k
    const float* __restrict__ bias,  // g*160 + j*16 + d
    float* __restrict__ out)         // (b, j, d)
{
    const int B = blockIdx.x, nwg = gridDim.x;   // 640
    const int idx = ((nwg & 7) == 0) ? (B & 7) * (nwg >> 3) + (B >> 3) : B;
    const int bq = idx / J_;
    const int j  = idx - bq * J_;
    const int t  = threadIdx.x;
    const int u  = t >> 7;            // unit 0..3 (2 waves each, wave-aligned)
    const int tl = t & 127;           // unit-local thread
    const int b  = bq * UN_ + u;
    const int wl = tl >> 6;           // wave-in-unit (0,1)
    const int lane = t & 63;
    const int g = tl >> 2, c = tl & 3;  // group 0..31, 4 lanes/group

    __shared__ float Wk[G_ * GSW_];                 // 18.9 KB shared by 4 units
    __shared__ __align__(16) float ylds[UN_][G_ * YS_];
    __shared__ __align__(16) float slds[UN_][D_];
    __shared__ float dsum[UN_][2];

    // ---- x preload (per unit): 2 aligned float4 + 1 scalar per k ----
    float xv[8][9];
    {
        const float* xb = x + (size_t)b * 9216 + (size_t)g * 288 + 4 * c;
        #pragma unroll
        for (int k = 0; k < 8; ++k) {
            const float4 a0 = *(const float4*)(xb + k * 36);
            const float4 a1 = *(const float4*)(xb + k * 36 + 16);
            xv[k][0] = a0.x; xv[k][1] = a0.y; xv[k][2] = a0.z; xv[k][3] = a0.w;
            xv[k][4] = a1.x; xv[k][5] = a1.y; xv[k][6] = a1.z; xv[k][7] = a1.w;
            xv[k][8] = xb[k * 36 + 32 - 3 * c];   // = row + 32 + c
        }
    }

    // ---- stage Wk ([g][k][d], bias as k=8): 512 threads = 512 (g,d) items ----
    {
        const int gg = t >> 4, d = t & 15;
        const float* src = Wt + (size_t)gg * 1280 + j * 128 + d * 8;
        const float4 a0 = *(const float4*)(src);
        const float4 a1 = *(const float4*)(src + 4);
        float* dst = Wk + gg * GSW_ + d;
        dst[0]   = a0.x; dst[16]  = a0.y; dst[32]  = a0.z; dst[48]  = a0.w;
        dst[64]  = a1.x; dst[80]  = a1.y; dst[96]  = a1.z; dst[112] = a1.w;
        dst[128] = bias[gg * 160 + j * 16 + d];
    }
    __syncthreads();

    float b_loc[9] = {0.f,0.f,0.f,0.f,0.f,0.f,0.f,0.f,0.f};
    const float EPS = 2.220446049250313e-16f;

    #pragma unroll 1
    for (int it = 0; it < 3; ++it) {
        // ---- e-weighted x sums ----
        float yp[8] = {0.f,0.f,0.f,0.f,0.f,0.f,0.f,0.f};
        float esum;
        if (it == 0) {
            #pragma unroll
            for (int q = 0; q < 9; ++q) {
                #pragma unroll
                for (int k = 0; k < 8; ++k) yp[k] += xv[k][q];
            }
            esum = 9.f;
        } else {
            esum = 0.f;
            #pragma unroll
            for (int q = 0; q < 9; ++q) {
                const float e = __expf(b_loc[q]);
                esum += e;
                #pragma unroll
                for (int k = 0; k < 8; ++k) yp[k] += e * xv[k][q];
            }
        }
        // 4-lane group reduce -> y[g,k], C_g
        #pragma unroll
        for (int k = 0; k < 8; ++k) {
            yp[k] += __shfl_xor(yp[k], 1);
            yp[k] += __shfl_xor(yp[k], 2);
        }
        esum += __shfl_xor(esum, 1);
        esum += __shfl_xor(esum, 2);
        if (c == 0) {
            float4 w0; w0.x = yp[0]; w0.y = yp[1]; w0.z = yp[2]; w0.w = yp[3];
            float4 w1; w1.x = yp[4]; w1.y = yp[5]; w1.z = yp[6]; w1.w = yp[7];
            *(float4*)(ylds[u] + g * YS_)     = w0;
            *(float4*)(ylds[u] + g * YS_ + 4) = w1;
            ylds[u][g * YS_ + 8] = esum;           // C_g
        }
        // denom: bits 2..5 butterfly sums this wave's 16 distinct groups once each
        float ws = esum;
        ws += __shfl_xor(ws, 4);  ws += __shfl_xor(ws, 8);
        ws += __shfl_xor(ws, 16); ws += __shfl_xor(ws, 32);
        if (lane == 0) dsum[u][wl] = ws;
        __syncthreads();                            // barrier 1
        const float denom = dsum[u][0] + dsum[u][1];

        // ---- s[d] = sum_{g,k} Wk[g][k][d] * y[g][k] (incl. bias*C_g) ----
        {
            const int d = tl >> 3, gg0 = tl & 7;
            float sp = 0.f;
            #pragma unroll
            for (int gi = 0; gi < 4; ++gi) {
                const int gg = gg0 + 8 * gi;
                const float* wr = Wk + gg * GSW_ + d;
                const float* yr = ylds[u] + gg * YS_;
                const float4 y0 = *(const float4*)(yr);
                const float4 y1 = *(const float4*)(yr + 4);
                const float  y8 = yr[8];
                const float sp0 = wr[0]  * y0.x + wr[16] * y0.y + wr[32] * y0.z + wr[48]  * y0.w;
                const float sp1 = wr[64] * y1.x + wr[80] * y1.y + wr[96] * y1.z + wr[112] * y1.w;
                sp += sp0 + sp1 + wr[128] * y8;
            }
            sp += __shfl_xor(sp, 1); sp += __shfl_xor(sp, 2); sp += __shfl_xor(sp, 4);
            if ((tl & 7) == 0) slds[u][d] = sp;
        }
        __syncthreads();                            // barrier 2

        if (it < 2) {
            // ---- blocked squash + u[g,k] partial dots ----
            float ssq = 0.f, ua = 0.f, ub = 0.f, u8v = 0.f;
            const float* wgc = Wk + g * GSW_;
            #pragma unroll
            for (int m = 0; m < 4; ++m) {
                const float4 s4 = ((const float4*)slds[u])[m];
                ssq += s4.x * s4.x + s4.y * s4.y + s4.z * s4.z + s4.w * s4.w;
                const float* wa = wgc + c * 16 + 4 * m;
                const float* wb = wgc + (c + 4) * 16 + 4 * m;
                const float* w8 = wgc + 128 + 4 * m;
                ua  += s4.x * wa[0] + s4.y * wa[1] + s4.z * wa[2] + s4.w * wa[3];
                ub  += s4.x * wb[0] + s4.y * wb[1] + s4.z * wb[2] + s4.w * wb[3];
                u8v += s4.x * w8[0] + s4.y * w8[1] + s4.z * w8[2] + s4.w * w8[3];
            }
            const float alpha = 1.f / denom;
            const float n2    = ssq * alpha * alpha;
            const float nrm   = sqrtf(n2);
            const float coeff = (n2 / (1.f + n2)) / (nrm + EPS);
            const float beta  = alpha * coeff;
            ua *= beta; ub *= beta; u8v *= beta;

            // gather u[0..7] across the 4-lane group (6 shfl)
            const float p1a = __shfl_xor(ua, 1);
            const float p1b = __shfl_xor(ub, 1);
            const bool  o1  = (c & 1) != 0;
            const float v0 = o1 ? p1a : ua;
            const float v1 = o1 ? ua  : p1a;
            const float v4 = o1 ? p1b : ub;
            const float v5 = o1 ? ub  : p1b;
            const float q0 = __shfl_xor(v0, 2);
            const float q1 = __shfl_xor(v1, 2);
            const float q4 = __shfl_xor(v4, 2);
            const float q5 = __shfl_xor(v5, 2);
            const bool  o2 = (c & 2) != 0;
            float uk[8];
            uk[0] = o2 ? q0 : v0;  uk[1] = o2 ? q1 : v1;
            uk[2] = o2 ? v0 : q0;  uk[3] = o2 ? v1 : q1;
            uk[4] = o2 ? q4 : v4;  uk[5] = o2 ? q5 : v5;
            uk[6] = o2 ? v4 : q4;  uk[7] = o2 ? v5 : q5;
            // ---- b_i += u . x_i + u_bias ----
            #pragma unroll
            for (int q = 0; q < 9; ++q) {
                float acc = u8v;
                #pragma unroll
                for (int k = 0; k < 8; ++k) acc += uk[k] * xv[k][q];
                b_loc[q] += acc;
            }
        } else {
            // ---- final squash + output ----
            float ssq = 0.f;
            #pragma unroll
            for (int m = 0; m < 4; ++m) {
                const float4 s4 = ((const float4*)slds[u])[m];
                ssq += s4.x * s4.x + s4.y * s4.y + s4.z * s4.z + s4.w * s4.w;
            }
            const float alpha = 1.f / denom;
            const float n2    = ssq * alpha * alpha;
            const float nrm   = sqrtf(n2);
            const float coeff = (n2 / (1.f + n2)) / (nrm + EPS);
            const float beta  = alpha * coeff;
            if (tl < D_) out[((size_t)b * J_ + j) * D_ + tl] = slds[u][tl] * beta;
        }
    }
}

extern "C" void kernel_launch(void* const* d_in, const int* in_sizes, int n_in,
                              void* d_out, int out_size, void* d_ws, size_t ws_size,
                              hipStream_t stream) {
    const float* x    = (const float*)d_in[0];
    const float* Wt   = (const float*)d_in[1];
    const float* bias = (const float*)d_in[2];
    float* out        = (float*)d_out;

    const int bs = in_sizes[0] / 9216;       // 256
    dim3 grid((bs / UN_) * J_);              // 640
    dim3 block(NT_);
    caps_route_kernel<<<grid, block, 0, stream>>>(x, Wt, bias, out);
}

// Round 12
// 26.740 us; speedup vs baseline: 1.2246x; 1.2246x over previous
//
#include <hip/hip_runtime.h>
#include <math.h>

// CapLayer fused, R12: factorized routing (no pred), ONE barrier per iter.
// R11 refuted the dispatch-floor theory (640 WGs was WORSE); R10 ruled out
// VMEM-issue. Remaining suspect: per-block serial latency (barriers + LDS
// round-trips). This round: each wave computes its own 16-group partial of
// s[d] fully in-register (quad reduce -> per-lane 9x ds_read_b128 dot ->
// g-bit butterfly), one float4 LDS write + ONE __syncthreads per iteration
// (4 barriers total vs 7). ylds eliminated. it=0 specialized (C_g=36,
// denom=1152 exact, no esum reduction).
// NO launch_bounds min-waves (R2/R3/R7: VGPR caps below working set spill).

#define G_    32
#define J_    10
#define D_    16
#define NT_   128
#define GSW_  148

__global__ __launch_bounds__(NT_) void caps_route_kernel(
    const float* __restrict__ x,     // (b, g*8+k, s) flat b*9216 + g*288 + k*36 + s
    const float* __restrict__ Wt,    // (g, j*16+d, k) flat g*1280 + (j*16+d)*8 + k
    const float* __restrict__ bias,  // g*160 + j*16 + d
    float* __restrict__ out)         // (b, j, d)
{
    const int B = blockIdx.x, nwg = gridDim.x;
    const int bj = ((nwg & 7) == 0) ? (B & 7) * (nwg >> 3) + (B >> 3) : B;
    const int b = bj / J_, j = bj - b * J_;
    const int t = threadIdx.x;
    const int lane = t & 63, wid = t >> 6;
    const int g = t >> 2, c = t & 3;     // group 0..31, 4 lanes/group

    __shared__ float Wk[G_ * GSW_];               // 18.9 KB, [g][k][d] (+bias k=8)
    __shared__ __align__(16) float swl[2][2][D_]; // [buf][wave][d] s-partials
    __shared__ float esw[2][2];                   // [buf][wave] exp-sum partials

    // ---- x preload: 2 aligned float4 + 1 scalar per k (lane c owns
    //      s in {4c..4c+3, 16+4c..19+4c, 32+c}) ----
    float xv[8][9];
    {
        const float* xb = x + (size_t)b * 9216 + (size_t)g * 288 + 4 * c;
        #pragma unroll
        for (int k = 0; k < 8; ++k) {
            const float4 a0 = *(const float4*)(xb + k * 36);
            const float4 a1 = *(const float4*)(xb + k * 36 + 16);
            xv[k][0] = a0.x; xv[k][1] = a0.y; xv[k][2] = a0.z; xv[k][3] = a0.w;
            xv[k][4] = a1.x; xv[k][5] = a1.y; xv[k][6] = a1.z; xv[k][7] = a1.w;
            xv[k][8] = xb[k * 36 + 32 - 3 * c];   // = row + 32 + c
        }
    }

    // ---- stage Wk transposed ([g][k][d]) + bias as k=8 row ----
    #pragma unroll
    for (int rr = 0; rr < 4; ++rr) {
        const int idx = t + rr * NT_;
        const int gg = idx >> 4, d = idx & 15;
        const float* src = Wt + (size_t)gg * 1280 + j * 128 + d * 8;
        const float4 a0 = *(const float4*)(src);
        const float4 a1 = *(const float4*)(src + 4);
        float* dst = Wk + gg * GSW_ + d;
        dst[0]   = a0.x; dst[16]  = a0.y; dst[32]  = a0.z; dst[48]  = a0.w;
        dst[64]  = a1.x; dst[80]  = a1.y; dst[96]  = a1.z; dst[112] = a1.w;
        dst[128] = bias[gg * 160 + j * 16 + d];
    }
    __syncthreads();                               // barrier 0 (staging)

    float b_loc[9] = {0.f,0.f,0.f,0.f,0.f,0.f,0.f,0.f,0.f};
    const float EPS = 2.220446049250313e-16f;

    #pragma unroll 1
    for (int it = 0; it < 3; ++it) {
        const int kb = it & 1;

        // ---- e-weighted x sums over this thread's 9 s's ----
        float yp[8] = {0.f,0.f,0.f,0.f,0.f,0.f,0.f,0.f};
        float esum = 0.f;
        if (it == 0) {
            #pragma unroll
            for (int q = 0; q < 9; ++q) {
                #pragma unroll
                for (int k = 0; k < 8; ++k) yp[k] += xv[k][q];
            }
        } else {
            #pragma unroll
            for (int q = 0; q < 9; ++q) {
                const float e = __expf(b_loc[q]);
                esum += e;
                #pragma unroll
                for (int k = 0; k < 8; ++k) yp[k] += e * xv[k][q];
            }
        }
        // quad reduce: every lane gets y[g][k] and C_g
        #pragma unroll
        for (int k = 0; k < 8; ++k) {
            yp[k] += __shfl_xor(yp[k], 1);
            yp[k] += __shfl_xor(yp[k], 2);
        }
        if (it > 0) { esum += __shfl_xor(esum, 1); esum += __shfl_xor(esum, 2); }
        const float cg = (it == 0) ? 36.f : esum;

        // ---- per-lane s-partial for d = 4c..4c+3 over its group g ----
        float part[4];
        const float* wg = Wk + g * GSW_ + 4 * c;
        {
            const float4 wb = *(const float4*)(wg + 128);   // bias row (k=8)
            part[0] = wb.x * cg; part[1] = wb.y * cg;
            part[2] = wb.z * cg; part[3] = wb.w * cg;
            #pragma unroll
            for (int k = 0; k < 8; ++k) {
                const float4 wv = *(const float4*)(wg + k * 16);
                part[0] += wv.x * yp[k]; part[1] += wv.y * yp[k];
                part[2] += wv.z * yp[k]; part[3] += wv.w * yp[k];
            }
        }
        // butterfly over g-bits (xor 4,8,16,32): sums the wave's 16 groups
        #pragma unroll
        for (int off = 4; off <= 32; off <<= 1) {
            #pragma unroll
            for (int m = 0; m < 4; ++m) part[m] += __shfl_xor(part[m], off);
            if (it > 0) esum += __shfl_xor(esum, off);
        }
        // lanes 0..3 hold s_w[4c..4c+3] (c == lane)
        if (lane < 4) {
            float4 pw; pw.x = part[0]; pw.y = part[1]; pw.z = part[2]; pw.w = part[3];
            *(float4*)(&swl[kb][wid][4 * lane]) = pw;
            if (lane == 0) esw[kb][wid] = esum;
        }
        __syncthreads();                           // barrier (1 per iter)

        const float denom = (it == 0) ? 1152.f : (esw[kb][0] + esw[kb][1]);

        if (it < 2) {
            // ---- blocked squash + u[g,k] partial dots (4 s-values live) ----
            float ssq = 0.f, ua = 0.f, ub = 0.f, u8v = 0.f;
            const float* wgc = Wk + g * GSW_;
            #pragma unroll
            for (int m = 0; m < 4; ++m) {
                const float4 sa = ((const float4*)swl[kb][0])[m];
                const float4 sb = ((const float4*)swl[kb][1])[m];
                float4 s4; s4.x = sa.x + sb.x; s4.y = sa.y + sb.y;
                           s4.z = sa.z + sb.z; s4.w = sa.w + sb.w;
                ssq += s4.x * s4.x + s4.y * s4.y + s4.z * s4.z + s4.w * s4.w;
                const float* wa = wgc + c * 16 + 4 * m;
                const float* wb = wgc + (c + 4) * 16 + 4 * m;
                const float* w8 = wgc + 128 + 4 * m;
                ua  += s4.x * wa[0] + s4.y * wa[1] + s4.z * wa[2] + s4.w * wa[3];
                ub  += s4.x * wb[0] + s4.y * wb[1] + s4.z * wb[2] + s4.w * wb[3];
                u8v += s4.x * w8[0] + s4.y * w8[1] + s4.z * w8[2] + s4.w * w8[3];
            }
            const float alpha = 1.f / denom;
            const float n2    = ssq * alpha * alpha;
            const float nrm   = sqrtf(n2);
            const float coeff = (n2 / (1.f + n2)) / (nrm + EPS);
            const float beta  = alpha * coeff;
            ua *= beta; ub *= beta; u8v *= beta;

            // gather u[0..7] across the 4-lane group (6 shfl)
            const float p1a = __shfl_xor(ua, 1);
            const float p1b = __shfl_xor(ub, 1);
            const bool  o1  = (c & 1) != 0;
            const float v0 = o1 ? p1a : ua;
            const float v1 = o1 ? ua  : p1a;
            const float v4 = o1 ? p1b : ub;
            const float v5 = o1 ? ub  : p1b;
            const float q0 = __shfl_xor(v0, 2);
            const float q1 = __shfl_xor(v1, 2);
            const float q4 = __shfl_xor(v4, 2);
            const float q5 = __shfl_xor(v5, 2);
            const bool  o2 = (c & 2) != 0;
            float uk[8];
            uk[0] = o2 ? q0 : v0;  uk[1] = o2 ? q1 : v1;
            uk[2] = o2 ? v0 : q0;  uk[3] = o2 ? v1 : q1;
            uk[4] = o2 ? q4 : v4;  uk[5] = o2 ? q5 : v5;
            uk[6] = o2 ? v4 : q4;  uk[7] = o2 ? v5 : q5;
            // ---- b_i += u . x_i + u_bias ----
            #pragma unroll
            for (int q = 0; q < 9; ++q) {
                float acc = u8v;
                #pragma unroll
                for (int k = 0; k < 8; ++k) acc += uk[k] * xv[k][q];
                b_loc[q] += acc;
            }
        } else {
            // ---- final squash + output ----
            float ssq = 0.f;
            #pragma unroll
            for (int m = 0; m < 4; ++m) {
                const float4 sa = ((const float4*)swl[kb][0])[m];
                const float4 sb = ((const float4*)swl[kb][1])[m];
                const float sx = sa.x + sb.x, sy = sa.y + sb.y;
                const float sz = sa.z + sb.z, sw = sa.w + sb.w;
                ssq += sx * sx + sy * sy + sz * sz + sw * sw;
            }
            const float alpha = 1.f / denom;
            const float n2    = ssq * alpha * alpha;
            const float nrm   = sqrtf(n2);
            const float coeff = (n2 / (1.f + n2)) / (nrm + EPS);
            const float beta  = alpha * coeff;
            if (t < D_) {
                const float sd = swl[kb][0][t] + swl[kb][1][t];
                out[(size_t)bj * D_ + t] = sd * beta;
            }
        }
    }
}

extern "C" void kernel_launch(void* const* d_in, const int* in_sizes, int n_in,
                              void* d_out, int out_size, void* d_ws, size_t ws_size,
                              hipStream_t stream) {
    const float* x    = (const float*)d_in[0];
    const float* Wt   = (const float*)d_in[1];
    const float* bias = (const float*)d_in[2];
    float* out        = (float*)d_out;

    const int bs = in_sizes[0] / 9216;   // 256
    dim3 grid(bs * J_);                  // 2560
    dim3 block(NT_);
    caps_route_kernel<<<grid, block, 0, stream>>>(x, Wt, bias, out);
}

// Round 13
// 25.182 us; speedup vs baseline: 1.3004x; 1.0619x over previous
//
#include <hip/hip_runtime.h>
#include <math.h>

// CapLayer fused, R13 = R12 + DPP quad_perm for all xor1/xor2 lane exchanges.
// R9/R10/R12 tie at 26.6-26.8us across 3x VMEM cut and 7->4 barrier cut ->
// the invariant is the DS pipe: ~190 DS ops/thread (ds_read_b128 + one
// ds_bpermute per __shfl_xor) ~= 11us/CU of LDS-pipe occupancy, the largest
// identified consumer. This round converts every xor1/xor2 exchange (quad
// reduce, esum, u-gather: ~64 DS ops/thread, -33%) to DPP quad_perm adds on
// the VALU pipe. Everything else identical to R12 (clean A/B).
// NO launch_bounds min-waves (R2/R3/R7: VGPR caps below working set spill).

#define G_    32
#define J_    10
#define D_    16
#define NT_   128
#define GSW_  148

__device__ __forceinline__ float dpp_add_x1(float v) {   // v += lane^1 partner
    const int s = __builtin_amdgcn_update_dpp(0, __float_as_int(v), 0xB1, 0xF, 0xF, true);
    return v + __int_as_float(s);
}
__device__ __forceinline__ float dpp_add_x2(float v) {   // v += lane^2 partner
    const int s = __builtin_amdgcn_update_dpp(0, __float_as_int(v), 0x4E, 0xF, 0xF, true);
    return v + __int_as_float(s);
}
__device__ __forceinline__ float dpp_x1(float v) {       // value from lane^1
    return __int_as_float(__builtin_amdgcn_update_dpp(0, __float_as_int(v), 0xB1, 0xF, 0xF, true));
}
__device__ __forceinline__ float dpp_x2(float v) {       // value from lane^2
    return __int_as_float(__builtin_amdgcn_update_dpp(0, __float_as_int(v), 0x4E, 0xF, 0xF, true));
}

__global__ __launch_bounds__(NT_) void caps_route_kernel(
    const float* __restrict__ x,     // (b, g*8+k, s) flat b*9216 + g*288 + k*36 + s
    const float* __restrict__ Wt,    // (g, j*16+d, k) flat g*1280 + (j*16+d)*8 + k
    const float* __restrict__ bias,  // g*160 + j*16 + d
    float* __restrict__ out)         // (b, j, d)
{
    const int B = blockIdx.x, nwg = gridDim.x;
    const int bj = ((nwg & 7) == 0) ? (B & 7) * (nwg >> 3) + (B >> 3) : B;
    const int b = bj / J_, j = bj - b * J_;
    const int t = threadIdx.x;
    const int lane = t & 63, wid = t >> 6;
    const int g = t >> 2, c = t & 3;     // group 0..31, 4 lanes/group

    __shared__ float Wk[G_ * GSW_];               // 18.9 KB, [g][k][d] (+bias k=8)
    __shared__ __align__(16) float swl[2][2][D_]; // [buf][wave][d] s-partials
    __shared__ float esw[2][2];                   // [buf][wave] exp-sum partials

    // ---- x preload: 2 aligned float4 + 1 scalar per k (lane c owns
    //      s in {4c..4c+3, 16+4c..19+4c, 32+c}) ----
    float xv[8][9];
    {
        const float* xb = x + (size_t)b * 9216 + (size_t)g * 288 + 4 * c;
        #pragma unroll
        for (int k = 0; k < 8; ++k) {
            const float4 a0 = *(const float4*)(xb + k * 36);
            const float4 a1 = *(const float4*)(xb + k * 36 + 16);
            xv[k][0] = a0.x; xv[k][1] = a0.y; xv[k][2] = a0.z; xv[k][3] = a0.w;
            xv[k][4] = a1.x; xv[k][5] = a1.y; xv[k][6] = a1.z; xv[k][7] = a1.w;
            xv[k][8] = xb[k * 36 + 32 - 3 * c];   // = row + 32 + c
        }
    }

    // ---- stage Wk transposed ([g][k][d]) + bias as k=8 row ----
    #pragma unroll
    for (int rr = 0; rr < 4; ++rr) {
        const int idx = t + rr * NT_;
        const int gg = idx >> 4, d = idx & 15;
        const float* src = Wt + (size_t)gg * 1280 + j * 128 + d * 8;
        const float4 a0 = *(const float4*)(src);
        const float4 a1 = *(const float4*)(src + 4);
        float* dst = Wk + gg * GSW_ + d;
        dst[0]   = a0.x; dst[16]  = a0.y; dst[32]  = a0.z; dst[48]  = a0.w;
        dst[64]  = a1.x; dst[80]  = a1.y; dst[96]  = a1.z; dst[112] = a1.w;
        dst[128] = bias[gg * 160 + j * 16 + d];
    }
    __syncthreads();                               // barrier 0 (staging)

    float b_loc[9] = {0.f,0.f,0.f,0.f,0.f,0.f,0.f,0.f,0.f};
    const float EPS = 2.220446049250313e-16f;

    #pragma unroll 1
    for (int it = 0; it < 3; ++it) {
        const int kb = it & 1;

        // ---- e-weighted x sums over this thread's 9 s's ----
        float yp[8] = {0.f,0.f,0.f,0.f,0.f,0.f,0.f,0.f};
        float esum = 0.f;
        if (it == 0) {
            #pragma unroll
            for (int q = 0; q < 9; ++q) {
                #pragma unroll
                for (int k = 0; k < 8; ++k) yp[k] += xv[k][q];
            }
        } else {
            #pragma unroll
            for (int q = 0; q < 9; ++q) {
                const float e = __expf(b_loc[q]);
                esum += e;
                #pragma unroll
                for (int k = 0; k < 8; ++k) yp[k] += e * xv[k][q];
            }
        }
        // quad reduce via DPP (VALU pipe, no DS): every lane gets y[g][k], C_g
        #pragma unroll
        for (int k = 0; k < 8; ++k) {
            yp[k] = dpp_add_x1(yp[k]);
            yp[k] = dpp_add_x2(yp[k]);
        }
        if (it > 0) { esum = dpp_add_x1(esum); esum = dpp_add_x2(esum); }
        const float cg = (it == 0) ? 36.f : esum;

        // ---- per-lane s-partial for d = 4c..4c+3 over its group g ----
        float part[4];
        const float* wg = Wk + g * GSW_ + 4 * c;
        {
            const float4 wb = *(const float4*)(wg + 128);   // bias row (k=8)
            part[0] = wb.x * cg; part[1] = wb.y * cg;
            part[2] = wb.z * cg; part[3] = wb.w * cg;
            #pragma unroll
            for (int k = 0; k < 8; ++k) {
                const float4 wv = *(const float4*)(wg + k * 16);
                part[0] += wv.x * yp[k]; part[1] += wv.y * yp[k];
                part[2] += wv.z * yp[k]; part[3] += wv.w * yp[k];
            }
        }
        // butterfly over g-bits (xor 4,8,16,32): sums the wave's 16 groups
        #pragma unroll
        for (int off = 4; off <= 32; off <<= 1) {
            #pragma unroll
            for (int m = 0; m < 4; ++m) part[m] += __shfl_xor(part[m], off);
            if (it > 0) esum += __shfl_xor(esum, off);
        }
        // lanes 0..3 hold s_w[4c..4c+3] (c == lane)
        if (lane < 4) {
            float4 pw; pw.x = part[0]; pw.y = part[1]; pw.z = part[2]; pw.w = part[3];
            *(float4*)(&swl[kb][wid][4 * lane]) = pw;
            if (lane == 0) esw[kb][wid] = esum;
        }
        __syncthreads();                           // barrier (1 per iter)

        const float denom = (it == 0) ? 1152.f : (esw[kb][0] + esw[kb][1]);

        if (it < 2) {
            // ---- blocked squash + u[g,k] partial dots (4 s-values live) ----
            float ssq = 0.f, ua = 0.f, ub = 0.f, u8v = 0.f;
            const float* wgc = Wk + g * GSW_;
            #pragma unroll
            for (int m = 0; m < 4; ++m) {
                const float4 sa = ((const float4*)swl[kb][0])[m];
                const float4 sb = ((const float4*)swl[kb][1])[m];
                float4 s4; s4.x = sa.x + sb.x; s4.y = sa.y + sb.y;
                           s4.z = sa.z + sb.z; s4.w = sa.w + sb.w;
                ssq += s4.x * s4.x + s4.y * s4.y + s4.z * s4.z + s4.w * s4.w;
                const float* wa = wgc + c * 16 + 4 * m;
                const float* wb = wgc + (c + 4) * 16 + 4 * m;
                const float* w8 = wgc + 128 + 4 * m;
                ua  += s4.x * wa[0] + s4.y * wa[1] + s4.z * wa[2] + s4.w * wa[3];
                ub  += s4.x * wb[0] + s4.y * wb[1] + s4.z * wb[2] + s4.w * wb[3];
                u8v += s4.x * w8[0] + s4.y * w8[1] + s4.z * w8[2] + s4.w * w8[3];
            }
            const float alpha = 1.f / denom;
            const float n2    = ssq * alpha * alpha;
            const float nrm   = sqrtf(n2);
            const float coeff = (n2 / (1.f + n2)) / (nrm + EPS);
            const float beta  = alpha * coeff;
            ua *= beta; ub *= beta; u8v *= beta;

            // gather u[0..7] across the 4-lane group (DPP exchanges, no DS)
            const float p1a = dpp_x1(ua);
            const float p1b = dpp_x1(ub);
            const bool  o1  = (c & 1) != 0;
            const float v0 = o1 ? p1a : ua;
            const float v1 = o1 ? ua  : p1a;
            const float v4 = o1 ? p1b : ub;
            const float v5 = o1 ? ub  : p1b;
            const float q0 = dpp_x2(v0);
            const float q1 = dpp_x2(v1);
            const float q4 = dpp_x2(v4);
            const float q5 = dpp_x2(v5);
            const bool  o2 = (c & 2) != 0;
            float uk[8];
            uk[0] = o2 ? q0 : v0;  uk[1] = o2 ? q1 : v1;
            uk[2] = o2 ? v0 : q0;  uk[3] = o2 ? v1 : q1;
            uk[4] = o2 ? q4 : v4;  uk[5] = o2 ? q5 : v5;
            uk[6] = o2 ? v4 : q4;  uk[7] = o2 ? v5 : q5;
            // ---- b_i += u . x_i + u_bias ----
            #pragma unroll
            for (int q = 0; q < 9; ++q) {
                float acc = u8v;
                #pragma unroll
                for (int k = 0; k < 8; ++k) acc += uk[k] * xv[k][q];
                b_loc[q] += acc;
            }
        } else {
            // ---- final squash + output ----
            float ssq = 0.f;
            #pragma unroll
            for (int m = 0; m < 4; ++m) {
                const float4 sa = ((const float4*)swl[kb][0])[m];
                const float4 sb = ((const float4*)swl[kb][1])[m];
                const float sx = sa.x + sb.x, sy = sa.y + sb.y;
                const float sz = sa.z + sb.z, sw = sa.w + sb.w;
                ssq += sx * sx + sy * sy + sz * sz + sw * sw;
            }
            const float alpha = 1.f / denom;
            const float n2    = ssq * alpha * alpha;
            const float nrm   = sqrtf(n2);
            const float coeff = (n2 / (1.f + n2)) / (nrm + EPS);
            const float beta  = alpha * coeff;
            if (t < D_) {
                const float sd = swl[kb][0][t] + swl[kb][1][t];
                out[(size_t)bj * D_ + t] = sd * beta;
            }
        }
    }
}

extern "C" void kernel_launch(void* const* d_in, const int* in_sizes, int n_in,
                              void* d_out, int out_size, void* d_ws, size_t ws_size,
                              hipStream_t stream) {
    const float* x    = (const float*)d_in[0];
    const float* Wt   = (const float*)d_in[1];
    const float* bias = (const float*)d_in[2];
    float* out        = (float*)d_out;

    const int bs = in_sizes[0] / 9216;   // 256
    dim3 grid(bs * J_);                  // 2560
    dim3 block(NT_);
    caps_route_kernel<<<grid, block, 0, stream>>>(x, Wt, bias, out);
}